// Round 1
// 322.555 us; speedup vs baseline: 1.0165x; 1.0165x over previous
//
#include <hip/hip_runtime.h>
#include <hip/hip_bf16.h>
#include <cstdint>
#include <cstddef>

// Problem constants
#define B_  4
#define S_  4096
#define A_  512
#define H_  1024
#define NH_ 16
#define HD_ 64

typedef __bf16 bf16;
typedef __bf16 bf16x8 __attribute__((ext_vector_type(8)));
typedef __bf16 bf16x4 __attribute__((ext_vector_type(4)));
typedef float  fx4    __attribute__((ext_vector_type(4)));

typedef __attribute__((address_space(3))) void LDS_v;
typedef const __attribute__((address_space(1))) void GLB_v;

__device__ __forceinline__ void gl_lds16(const void* g, void* l) {
    __builtin_amdgcn_global_load_lds((GLB_v*)g, (LDS_v*)l, 16, 0, 0);
}

__device__ __forceinline__ float sanf(float x) {
    if (x != x) return 0.f;                       // NaN -> 0
    if (fabsf(x) == __builtin_inff()) return x > 0.f ? 10000.f : -10000.f;
    return x;
}

// ---------------------------------------------------------------- fused cast (all 6 inputs, one dispatch)
__global__ __launch_bounds__(256) void cast_all(const float* __restrict__ hs,
                                                const float* __restrict__ at,
                                                const float* __restrict__ wq,
                                                const float* __restrict__ wk,
                                                const float* __restrict__ wv,
                                                const float* __restrict__ wo,
                                                bf16* __restrict__ dhs, bf16* __restrict__ dat,
                                                bf16* __restrict__ dwq, bf16* __restrict__ dwk,
                                                bf16* __restrict__ dwv, bf16* __restrict__ dwo) {
    int i = blockIdx.x * 256 + threadIdx.x;
    const float* s; bf16* d; int off;
    if (i < 4194304)      { s = hs; d = dhs; off = i; }
    else if (i < 4718592) { s = at; d = dat; off = i - 4194304; }
    else if (i < 4980736) { s = wq; d = dwq; off = i - 4718592; }
    else if (i < 5242880) { s = wk; d = dwk; off = i - 4980736; }
    else if (i < 5505024) { s = wv; d = dwv; off = i - 5242880; }
    else                  { s = wo; d = dwo; off = i - 5505024; }
    float4 v = ((const float4*)s)[off];
    bf16x4 o;
    o[0] = (bf16)sanf(v.x); o[1] = (bf16)sanf(v.y);
    o[2] = (bf16)sanf(v.z); o[3] = (bf16)sanf(v.w);
    *(bf16x4*)&d[(size_t)off * 4] = o;
}

// ---------------------------------------------------------------- fused QKV GEMM (one dispatch, 1280 blocks)
// R3 structure — the fastest measured (64.9 us): bf16 inputs via gl_lds16,
// direct scalar epilogue stores for Q/K, packed bf16x4 for V^T.
// id <1024: Q = hsb@wq^T (+bq) * log2e/8 -> Qb bf16
// id <1152: K = atb@wk^T (+bk)           -> Kb bf16
// else    : V = atb@wv^T (+bv)           -> Vtb bf16 transposed [(b*H+n)*512+a]
__global__ __launch_bounds__(256) void qkv_gemm(const bf16* __restrict__ hsb,
                                                const bf16* __restrict__ atb,
                                                const bf16* __restrict__ wqb,
                                                const bf16* __restrict__ wkb,
                                                const bf16* __restrict__ wvb,
                                                const float* __restrict__ bq,
                                                const float* __restrict__ bk,
                                                const float* __restrict__ bv,
                                                bf16* __restrict__ Qb,
                                                bf16* __restrict__ Kb,
                                                bf16* __restrict__ Vtb) {
    __shared__ __align__(16) bf16 As[128 * 32];
    __shared__ __align__(16) bf16 Bs[128 * 32];

    const int id = blockIdx.x;
    int mode, m0, n0;
    const bf16 *A, *Bt; const float* bias;
    if (id < 1024)      { mode = 0; m0 = (id & 127) * 128; n0 = (id >> 7) * 128; A = hsb; Bt = wqb; bias = bq; }
    else if (id < 1152) { int t = id - 1024; mode = 1; m0 = (t & 15) * 128; n0 = (t >> 4) * 128; A = atb; Bt = wkb; bias = bk; }
    else                { int t = id - 1152; mode = 2; m0 = (t & 15) * 128; n0 = (t >> 4) * 128; A = atb; Bt = wvb; bias = bv; }

    const int tid  = threadIdx.x;
    const int lane = tid & 63;
    const int wv   = tid >> 6;
    const int wr   = wv >> 1, wc = wv & 1;
    const int lr   = lane & 15, kq = lane >> 4;

    fx4 acc[4][4] = {};

    const bf16* Ag = A  + (size_t)m0 * 1024;
    const bf16* Bg = Bt + (size_t)n0 * 1024;
    const int c0 = tid, c1 = tid + 256;
    const int row0 = c0 >> 2, kc0 = c0 & 3;
    const int row1 = c1 >> 2, kc1 = c1 & 3;

    for (int k0 = 0; k0 < 1024; k0 += 32) {
        gl_lds16(Ag + (size_t)row0 * 1024 + k0 + kc0 * 8, &As[c0 * 8]);
        gl_lds16(Ag + (size_t)row1 * 1024 + k0 + kc1 * 8, &As[c1 * 8]);
        gl_lds16(Bg + (size_t)row0 * 1024 + k0 + kc0 * 8, &Bs[c0 * 8]);
        gl_lds16(Bg + (size_t)row1 * 1024 + k0 + kc1 * 8, &Bs[c1 * 8]);
        __syncthreads();
        bf16x8 af[4], bfr[4];
#pragma unroll
        for (int i = 0; i < 4; i++) af[i]  = *(const bf16x8*)&As[(wr * 64 + i * 16 + lr) * 32 + kq * 8];
#pragma unroll
        for (int j = 0; j < 4; j++) bfr[j] = *(const bf16x8*)&Bs[(wc * 64 + j * 16 + lr) * 32 + kq * 8];
#pragma unroll
        for (int i = 0; i < 4; i++)
#pragma unroll
            for (int j = 0; j < 4; j++)
                acc[i][j] = __builtin_amdgcn_mfma_f32_16x16x32_bf16(af[i], bfr[j], acc[i][j], 0, 0, 0);
        __syncthreads();
    }

    float bb[4];
#pragma unroll
    for (int j = 0; j < 4; j++) bb[j] = bias[n0 + wc * 64 + j * 16 + lr];

    if (mode == 0) {
        const float sc = 0.18033688011112042f;  // log2(e)/8 prescale for exp2-domain scores
#pragma unroll
        for (int i = 0; i < 4; i++) {
            int row = m0 + wr * 64 + i * 16 + kq * 4;
#pragma unroll
            for (int j = 0; j < 4; j++) {
                int col = n0 + wc * 64 + j * 16 + lr;
#pragma unroll
                for (int r = 0; r < 4; r++)
                    Qb[(size_t)(row + r) * 1024 + col] = (bf16)((acc[i][j][r] + bb[j]) * sc);
            }
        }
    } else if (mode == 1) {
#pragma unroll
        for (int i = 0; i < 4; i++) {
            int row = m0 + wr * 64 + i * 16 + kq * 4;
#pragma unroll
            for (int j = 0; j < 4; j++) {
                int col = n0 + wc * 64 + j * 16 + lr;
#pragma unroll
                for (int r = 0; r < 4; r++)
                    Kb[(size_t)(row + r) * 1024 + col] = (bf16)(acc[i][j][r] + bb[j]);
            }
        }
    } else {
        // V: transposed output, r-contiguous -> packed bf16x4 stores
#pragma unroll
        for (int i = 0; i < 4; i++) {
            int m = m0 + wr * 64 + i * 16 + kq * 4;  // m = b*512 + a
            int bidx = m >> 9, a = m & 511;
#pragma unroll
            for (int j = 0; j < 4; j++) {
                int col = n0 + wc * 64 + j * 16 + lr;
                bf16x4 o;
#pragma unroll
                for (int r = 0; r < 4; r++) o[r] = (bf16)(acc[i][j][r] + bb[j]);
                *(bf16x4*)&Vtb[((size_t)bidx * H_ + col) * A_ + a] = o;
            }
        }
    }
}

// ---------------------------------------------------------------- O-proj GEMM: delta bf16 = (ctx@Wo^T + bo) * rs
// R3 staging (gl_lds16, bf16 weights) + direct scalar bf16 stores (no LDS
// transpose — R4 showed it regresses) + bf16 output (halves write + LN read).
__global__ __launch_bounds__(256) void gemm_o(const bf16* __restrict__ A,
                                              const bf16* __restrict__ Bt,
                                              const float* __restrict__ bias,
                                              bf16* __restrict__ C,
                                              const float* __restrict__ rsp) {
    __shared__ __align__(16) bf16 As[128 * 32];
    __shared__ __align__(16) bf16 Bs[128 * 32];

    const int tid  = threadIdx.x;
    const int lane = tid & 63;
    const int wv   = tid >> 6;
    const int wr   = wv >> 1, wc = wv & 1;
    const int lr   = lane & 15, kq = lane >> 4;
    const int m0   = blockIdx.x * 128, n0 = blockIdx.y * 128;

    fx4 acc[4][4] = {};

    const bf16* Ag = A  + (size_t)m0 * 1024;
    const bf16* Bg = Bt + (size_t)n0 * 1024;
    const int c0 = tid, c1 = tid + 256;
    const int row0 = c0 >> 2, kc0 = c0 & 3;
    const int row1 = c1 >> 2, kc1 = c1 & 3;

    for (int k0 = 0; k0 < 1024; k0 += 32) {
        gl_lds16(Ag + (size_t)row0 * 1024 + k0 + kc0 * 8, &As[c0 * 8]);
        gl_lds16(Ag + (size_t)row1 * 1024 + k0 + kc1 * 8, &As[c1 * 8]);
        gl_lds16(Bg + (size_t)row0 * 1024 + k0 + kc0 * 8, &Bs[c0 * 8]);
        gl_lds16(Bg + (size_t)row1 * 1024 + k0 + kc1 * 8, &Bs[c1 * 8]);
        __syncthreads();
        bf16x8 af[4], bfr[4];
#pragma unroll
        for (int i = 0; i < 4; i++) af[i]  = *(const bf16x8*)&As[(wr * 64 + i * 16 + lr) * 32 + kq * 8];
#pragma unroll
        for (int j = 0; j < 4; j++) bfr[j] = *(const bf16x8*)&Bs[(wc * 64 + j * 16 + lr) * 32 + kq * 8];
#pragma unroll
        for (int i = 0; i < 4; i++)
#pragma unroll
            for (int j = 0; j < 4; j++)
                acc[i][j] = __builtin_amdgcn_mfma_f32_16x16x32_bf16(af[i], bfr[j], acc[i][j], 0, 0, 0);
        __syncthreads();
    }

    float bb[4];
#pragma unroll
    for (int j = 0; j < 4; j++) bb[j] = bias[n0 + wc * 64 + j * 16 + lr];
    float rs = fminf(fmaxf(rsp[0], 0.f), 0.3f);
#pragma unroll
    for (int i = 0; i < 4; i++) {
        int row = m0 + wr * 64 + i * 16 + kq * 4;
#pragma unroll
        for (int j = 0; j < 4; j++) {
            int col = n0 + wc * 64 + j * 16 + lr;
#pragma unroll
            for (int r = 0; r < 4; r++)
                C[(size_t)(row + r) * 1024 + col] = (bf16)(rs * (acc[i][j][r] + bb[j]));
        }
    }
}

// ---------------------------------------------------------------- attention
// S^T = K·Q^T keeps P in registers (A-operand layout via free k-permutation);
// permuted V^T LDS layout makes every PV B-fragment one conflict-free b128.
// R5: VALU diet — (a) dropped the dead fmax(.,LO) (masked lanes hit LO exactly
// via fmin vs cap; any s<LO contributes <2^-72, invisible in fp32);
// (b) exp2 results written straight into PV A-fragment layout pa[ks][stl]
// (kills 4 shufflevector repacks/tile); (c) denominator on the MFMA pipe:
// one ones-B MFMA per P-fragment gives D[s][*]=sum_a P[s][a] in acco's exact
// row layout (kq*4+r), broadcast across lr — no dloc adds, no shfl_xor
// reduce, no dnm LDS publish, one barrier fewer.
__global__ __launch_bounds__(256, 4) void attn_kernel(const bf16* __restrict__ Q,
                                                      const bf16* __restrict__ Kb,
                                                      const bf16* __restrict__ Vt,
                                                      const int* __restrict__ mask,
                                                      bf16* __restrict__ ctx) {
    __shared__ __align__(16) bf16 Qs[128 * 72];   // padded; reused for ctx staging
    __shared__ __align__(16) bf16 Ks[64 * 72];    // K [a][d], padded
    __shared__ __align__(16) bf16 Vts[64 * 72];   // V^T [d][a-permuted], padded
    __shared__ float smask[512];                  // caps: +/- 50*log2e

    const int tid  = threadIdx.x;
    const int lane = tid & 63;
    const int wv   = tid >> 6;
    const int lr   = lane & 15, kq = lane >> 4;
    const int st = blockIdx.x, h = blockIdx.y, b = blockIdx.z;
    const int m0 = b * S_ + st * 128;
    const float LO = -72.134752f;                 // -50*log2e

    // --- stage Q (padded, via VGPRs) + mask caps
    bf16x8 qtmp[4];
#pragma unroll
    for (int i = 0; i < 4; i++) {
        int c = tid + i * 256, row = c >> 3, ch = c & 7;
        qtmp[i] = *(const bf16x8*)(Q + (size_t)(m0 + row) * H_ + h * 64 + ch * 8);
    }
    smask[tid]       = (mask[b * A_ + tid] > 0)       ? -LO : LO;
    smask[tid + 256] = (mask[b * A_ + tid + 256] > 0) ? -LO : LO;
#pragma unroll
    for (int i = 0; i < 4; i++) {
        int c = tid + i * 256, row = c >> 3, ch = c & 7;
        *(bf16x8*)&Qs[row * 72 + ch * 8] = qtmp[i];
    }

    // staging coords
    const int srow = tid >> 2, sseg = tid & 3;
    const size_t kg = (size_t)(b * A_ + srow) * H_ + h * 64 + sseg * 16;
    const bf16* vrow = Vt + (size_t)(b * H_ + h * 64 + srow) * A_;
    const int va0 = 32 * (sseg >> 1) + 4 * ((2 * sseg) & 3);      // u=0 source base
    const int va1 = 32 * (sseg >> 1) + 4 * ((2 * sseg + 1) & 3);  // u=1 source base

    // prefetch tile 0
    bf16x8 kr0 = *(const bf16x8*)(Kb + kg);
    bf16x8 kr1 = *(const bf16x8*)(Kb + kg + 8);
    bf16x4 v00 = *(const bf16x4*)(vrow + va0);
    bf16x4 v01 = *(const bf16x4*)(vrow + va0 + 16);
    bf16x4 v10 = *(const bf16x4*)(vrow + va1);
    bf16x4 v11 = *(const bf16x4*)(vrow + va1 + 16);

    fx4 acco[2][4] = {};          // [st][dt] : ctx[s=wv*32+st*16+kq*4+r][d=dt*16+lr]
    fx4 accd[2] = {};             // denom:    D[s=...+kq*4+r] (all lr identical)

    bf16x8 vone;
#pragma unroll
    for (int e = 0; e < 8; e++) vone[e] = (bf16)1.0f;

    for (int it = 0; it < 8; it++) {
        const int a0 = it * 64;
        __syncthreads();  // prev compute done reading Ks/Vts (it=0: Q/mask writes ordered)
        *(bf16x8*)&Ks[srow * 72 + sseg * 16]      = kr0;
        *(bf16x8*)&Ks[srow * 72 + sseg * 16 + 8]  = kr1;
        *(bf16x8*)&Vts[srow * 72 + sseg * 16] =
            __builtin_shufflevector(v00, v01, 0, 1, 2, 3, 4, 5, 6, 7);
        *(bf16x8*)&Vts[srow * 72 + sseg * 16 + 8] =
            __builtin_shufflevector(v10, v11, 0, 1, 2, 3, 4, 5, 6, 7);
        __syncthreads();  // staging visible (lgkm only — no LDS-writing vmem in flight)

        if (it < 7) {     // register prefetch for it+1 (uniform branch)
            const size_t ko = kg + (size_t)(a0 + 64) * H_;
            kr0 = *(const bf16x8*)(Kb + ko);
            kr1 = *(const bf16x8*)(Kb + ko + 8);
            v00 = *(const bf16x4*)(vrow + a0 + 64 + va0);
            v01 = *(const bf16x4*)(vrow + a0 + 64 + va0 + 16);
            v10 = *(const bf16x4*)(vrow + a0 + 64 + va1);
            v11 = *(const bf16x4*)(vrow + a0 + 64 + va1 + 16);
        }

        // ---- S^T = K·Q^T  (M=a 64, N=s; wave owns s in [wv*32, wv*32+32))
        fx4 accs[4][2] = {};   // [mt][nt] : S^T[a=mt*16+kq*4+r][s=wv*32+nt*16+lr]
#pragma unroll
        for (int kk = 0; kk < 64; kk += 32) {
            bf16x8 kf[4], qf[2];
#pragma unroll
            for (int mt = 0; mt < 4; mt++)
                kf[mt] = *(const bf16x8*)&Ks[(mt * 16 + lr) * 72 + kk + kq * 8];
#pragma unroll
            for (int nt = 0; nt < 2; nt++)
                qf[nt] = *(const bf16x8*)&Qs[(wv * 32 + nt * 16 + lr) * 72 + kk + kq * 8];
#pragma unroll
            for (int mt = 0; mt < 4; mt++)
#pragma unroll
                for (int nt = 0; nt < 2; nt++)
                    accs[mt][nt] = __builtin_amdgcn_mfma_f32_16x16x32_bf16(kf[mt], qf[nt], accs[mt][nt], 0, 0, 0);
        }

        // ---- softmax numerator in-register, written directly into PV A-fragments
        bf16x8 pa[2][2];   // [ks][stl] : element (mt&1)*4+r <- P[a=a0+mt*16+kq*4+r][s-blk stl]
#pragma unroll
        for (int mt = 0; mt < 4; mt++) {
            fx4 cap = *(const fx4*)&smask[a0 + mt * 16 + kq * 4];
#pragma unroll
            for (int nt = 0; nt < 2; nt++) {
#pragma unroll
                for (int r = 0; r < 4; r++) {
                    float p = __builtin_amdgcn_exp2f(fminf(accs[mt][nt][r], cap[r]));
                    pa[mt >> 1][nt][(mt & 1) * 4 + r] = (bf16)p;
                }
            }
        }

        // ---- PV: ctx += P·V (B = V^T LDS, b128) ; denom += P·1 on the MFMA pipe
#pragma unroll
        for (int ks = 0; ks < 2; ks++) {
#pragma unroll
            for (int stl = 0; stl < 2; stl++)
                accd[stl] = __builtin_amdgcn_mfma_f32_16x16x32_bf16(pa[ks][stl], vone, accd[stl], 0, 0, 0);
#pragma unroll
            for (int dt = 0; dt < 4; dt++) {
                bf16x8 vf = *(const bf16x8*)&Vts[(dt * 16 + lr) * 72 + ks * 32 + kq * 8];
#pragma unroll
                for (int stl = 0; stl < 2; stl++)
                    acco[stl][dt] = __builtin_amdgcn_mfma_f32_16x16x32_bf16(pa[ks][stl], vf, acco[stl][dt], 0, 0, 0);
            }
        }
    }

    // ---- normalize from accd (every lane holds its rows' denominators) +
    //      stage ctx tile into Qs (own-wave rows only — no cross-wave hazard),
    //      then vectorized store
#pragma unroll
    for (int stl = 0; stl < 2; stl++) {
        float ri[4];
#pragma unroll
        for (int r = 0; r < 4; r++) ri[r] = __builtin_amdgcn_rcpf(accd[stl][r]);
#pragma unroll
        for (int dt = 0; dt < 4; dt++)
#pragma unroll
            for (int r = 0; r < 4; r++)
                Qs[(wv * 32 + stl * 16 + kq * 4 + r) * 72 + dt * 16 + lr] =
                    (bf16)(acco[stl][dt][r] * ri[r]);
    }
    __syncthreads();
#pragma unroll
    for (int i = 0; i < 4; i++) {
        int c = tid + i * 256, row = c >> 3, ch = c & 7;
        *(bf16x8*)&ctx[(size_t)(m0 + row) * H_ + h * 64 + ch * 8] = *(const bf16x8*)&Qs[row * 72 + ch * 8];
    }
}

// ---------------------------------------------------------------- LayerNorm: bf16 delta -> fp32 out
__global__ __launch_bounds__(256) void ln_kernel(const bf16* __restrict__ in,
                                                 float* __restrict__ out,
                                                 const float* __restrict__ gamma,
                                                 const float* __restrict__ beta) {
    __shared__ float red[8];
    const int tid = threadIdx.x;
    bf16x4 xb = *(const bf16x4*)&in[(size_t)blockIdx.x * 1024 + tid * 4];
    float x0 = (float)xb[0], x1 = (float)xb[1], x2 = (float)xb[2], x3 = (float)xb[3];
    float s = x0 + x1 + x2 + x3;
    float q = x0 * x0 + x1 * x1 + x2 * x2 + x3 * x3;
#pragma unroll
    for (int off = 32; off > 0; off >>= 1) {
        s += __shfl_down(s, off);
        q += __shfl_down(q, off);
    }
    if ((tid & 63) == 0) { red[(tid >> 6) * 2] = s; red[(tid >> 6) * 2 + 1] = q; }
    __syncthreads();
    s = red[0] + red[2] + red[4] + red[6];
    q = red[1] + red[3] + red[5] + red[7];
    float mean = s * (1.f / 1024.f);
    float var  = q * (1.f / 1024.f) - mean * mean;
    float inv  = rsqrtf(var + 1e-5f);
    float4 g  = ((const float4*)gamma)[tid];
    float4 bb = ((const float4*)beta)[tid];
    float4 y;
    y.x = (x0 - mean) * inv * g.x + bb.x;
    y.y = (x1 - mean) * inv * g.y + bb.y;
    y.z = (x2 - mean) * inv * g.z + bb.z;
    y.w = (x3 - mean) * inv * g.w + bb.w;
    ((float4*)(out + (size_t)blockIdx.x * 1024))[tid] = y;
}

// ---------------------------------------------------------------- launch
extern "C" void kernel_launch(void* const* d_in, const int* in_sizes, int n_in,
                              void* d_out, int out_size, void* d_ws, size_t ws_size,
                              hipStream_t stream) {
    const float* hs    = (const float*)d_in[0];
    const float* at    = (const float*)d_in[1];
    const int*   maskp = (const int*)d_in[2];
    const float* Wq    = (const float*)d_in[3];
    const float* bq    = (const float*)d_in[4];
    const float* Wk    = (const float*)d_in[5];
    const float* bk    = (const float*)d_in[6];
    const float* Wv    = (const float*)d_in[7];
    const float* bv    = (const float*)d_in[8];
    const float* Wo    = (const float*)d_in[9];
    const float* bo    = (const float*)d_in[10];
    const float* gamma = (const float*)d_in[11];
    const float* beta  = (const float*)d_in[12];
    const float* rsp   = (const float*)d_in[13];

    char* ws = (char*)d_ws;
    bf16* hsb = (bf16*)(ws + 0);          // 32 MB  [16384,1024]
    bf16* ctx = (bf16*)(ws + 0);          // alias (hs dead after qkv_gemm)
    bf16* atb = (bf16*)(ws + 33554432);   //  4 MB  [2048,1024]
    bf16* wqb = (bf16*)(ws + 37748736);   //  2 MB
    bf16* wkb = (bf16*)(ws + 39845888);   //  2 MB
    bf16* wvb = (bf16*)(ws + 41943040);   //  2 MB
    bf16* wob = (bf16*)(ws + 44040192);   //  2 MB
    bf16* Qb  = (bf16*)(ws + 46137344);   // 32 MB  [16384,1024] (prescaled)
    bf16* Ob  = Qb;                       // alias (Qb dead after attn) — bf16 delta
    bf16* Kb  = (bf16*)(ws + 79691776);   //  4 MB  [2048,1024]
    bf16* Vtb = (bf16*)(ws + 83886080);   //  4 MB  [B*H, 512] transposed

    cast_all<<<22528, 256, 0, stream>>>(hs, at, Wq, Wk, Wv, Wo,
                                        hsb, atb, wqb, wkb, wvb, wob);

    qkv_gemm<<<1280, 256, 0, stream>>>(hsb, atb, wqb, wkb, wvb,
                                       bq, bk, bv, Qb, Kb, Vtb);

    attn_kernel<<<dim3(32, 16, 4), 256, 0, stream>>>(Qb, Kb, Vtb, maskp, ctx);

    gemm_o<<<dim3(128, 8), 256, 0, stream>>>(ctx, wob, bo, Ob, rsp);
    ln_kernel<<<16384, 256, 0, stream>>>(Ob, (float*)d_out, gamma, beta);
}

// Round 3
// 319.398 us; speedup vs baseline: 1.0265x; 1.0099x over previous
//
#include <hip/hip_runtime.h>
#include <hip/hip_bf16.h>
#include <cstdint>
#include <cstddef>

// Problem constants
#define B_  4
#define S_  4096
#define A_  512
#define H_  1024
#define NH_ 16
#define HD_ 64

typedef __bf16 bf16;
typedef __bf16 bf16x8 __attribute__((ext_vector_type(8)));
typedef __bf16 bf16x4 __attribute__((ext_vector_type(4)));
typedef float  fx4    __attribute__((ext_vector_type(4)));

typedef __attribute__((address_space(3))) void LDS_v;
typedef const __attribute__((address_space(1))) void GLB_v;

__device__ __forceinline__ void gl_lds16(const void* g, void* l) {
    __builtin_amdgcn_global_load_lds((GLB_v*)g, (LDS_v*)l, 16, 0, 0);
}

__device__ __forceinline__ float sanf(float x) {
    if (x != x) return 0.f;                       // NaN -> 0
    if (fabsf(x) == __builtin_inff()) return x > 0.f ? 10000.f : -10000.f;
    return x;
}

// ---------------------------------------------------------------- fused cast (all 6 inputs, one dispatch)
__global__ __launch_bounds__(256) void cast_all(const float* __restrict__ hs,
                                                const float* __restrict__ at,
                                                const float* __restrict__ wq,
                                                const float* __restrict__ wk,
                                                const float* __restrict__ wv,
                                                const float* __restrict__ wo,
                                                bf16* __restrict__ dhs, bf16* __restrict__ dat,
                                                bf16* __restrict__ dwq, bf16* __restrict__ dwk,
                                                bf16* __restrict__ dwv, bf16* __restrict__ dwo) {
    int i = blockIdx.x * 256 + threadIdx.x;
    const float* s; bf16* d; int off;
    if (i < 4194304)      { s = hs; d = dhs; off = i; }
    else if (i < 4718592) { s = at; d = dat; off = i - 4194304; }
    else if (i < 4980736) { s = wq; d = dwq; off = i - 4718592; }
    else if (i < 5242880) { s = wk; d = dwk; off = i - 4980736; }
    else if (i < 5505024) { s = wv; d = dwv; off = i - 5242880; }
    else                  { s = wo; d = dwo; off = i - 5505024; }
    float4 v = ((const float4*)s)[off];
    bf16x4 o;
    o[0] = (bf16)sanf(v.x); o[1] = (bf16)sanf(v.y);
    o[2] = (bf16)sanf(v.z); o[3] = (bf16)sanf(v.w);
    *(bf16x4*)&d[(size_t)off * 4] = o;
}

// ---------------------------------------------------------------- 256x256 4-phase counted-vmcnt GEMM (R7)
// Geometry & schedule = m201 template (verified 1563 TF on this chip):
// 512 thr / 8 waves (2M x 4N), BK=64 as 2 K-halves of 32, 128 KiB dbuf LDS,
// st_16x32 swizzle (inverse-permuted global source + swizzled ds_read; gl_lds16
// dest linear), per phase {ds_read frags; stage 2 loads; barrier; lgkmcnt(0);
// setprio(1); 16 MFMA; setprio(0); [vmcnt(4) once per K-half-pair]; barrier}.
// vmcnt ledger (per wave, 2 loads per STG): ph1-end wait drains current tile's
// A1/B1 (read in ph2); ph3-end drains next tile's A0/B0 (read in next ph0).
// Each wave waits its OWN vmcnt BEFORE the barrier -> post-barrier all waves'
// halves are LDS-visible. vmcnt never 0 in main loop; drain only in peeled tile.
// emode 0: Q-projection (log2e/8 prescale); 1: O-proj (*rs clamp).
__global__ __launch_bounds__(512, 2) void gemm256(const bf16* __restrict__ A,
                                                  const bf16* __restrict__ Bt,
                                                  const float* __restrict__ bias,
                                                  bf16* __restrict__ C,
                                                  const int emode,
                                                  const float* __restrict__ rsp) {
    __shared__ __align__(16) bf16 lds[2][2][2][256][32];   // [buf][A/B][khalf][row][k] = 128 KiB

    const int tid  = threadIdx.x;
    const int lane = tid & 63;
    const int w8   = tid >> 6;               // wave 0..7
    const int wm   = w8 >> 2, wn = w8 & 3;   // wave grid 2(M) x 4(N)
    const int lr   = lane & 15, kq = lane >> 4;
    const int swz  = ((lr >> 3) & 1) << 4;   // read-side st_16x32 swizzle (elems)

    // XCD-aware bijective swizzle: 256 blocks, 8 XCDs x 32 contiguous tiles
    const int sid = ((blockIdx.x & 7) << 5) | (blockIdx.x >> 3);
    const int m0 = (sid & 63) << 8, n0 = (sid >> 6) << 8;

    // staging source: lane l covers granule g (16B) of its wave's 16-row block;
    // g = l ^ ((l>>5&1)<<1) pre-applies the inverse LDS swizzle.
    const int g = lane ^ (((lane >> 5) & 1) << 1);
    const bf16* Asrc = A  + (size_t)(m0 + w8 * 32 + (g >> 2)) * 1024 + (g & 3) * 8;
    const bf16* Bsrc = Bt + (size_t)(n0 + w8 * 32 + (g >> 2)) * 1024 + (g & 3) * 8;

#define STG(MS_, kh_, kt_, si_) do {                                                   \
        const bf16* s_ = (MS_ ? Bsrc : Asrc) + (kt_) * 64 + (kh_) * 32;                \
        gl_lds16(s_,                 &lds[si_][MS_][kh_][w8 * 32][0]      + lane * 8); \
        gl_lds16(s_ + (size_t)16384, &lds[si_][MS_][kh_][w8 * 32 + 16][0] + lane * 8); \
    } while (0)

#define DSRA(i_, ks_, bi_) (*(const bf16x8*)(&lds[bi_][0][ks_][0][0] + \
        ((((wm * 128 + (i_) * 16 + lr) * 32 + kq * 8)) ^ swz)))
#define DSRB(j_, ks_, bi_) (*(const bf16x8*)(&lds[bi_][1][ks_][0][0] + \
        ((((wn * 64 + (j_) * 16 + lr) * 32 + kq * 8)) ^ swz)))

    fx4 acc[8][4] = {};

    // prologue: stage all 4 halves of tile 0 (order A0,B0,A1,B1), wait first 2
    STG(0, 0, 0, 0); STG(1, 0, 0, 0); STG(0, 1, 0, 0); STG(1, 1, 0, 0);
    asm volatile("s_waitcnt vmcnt(4)" ::: "memory");
    __builtin_amdgcn_s_barrier();

    for (int kt = 0; kt < 15; ++kt) {
        const int bi = kt & 1, si = bi ^ 1, kn = kt + 1;
        bf16x8 af[4], bfr[4];

        // ---- ph0 (ks=0, frags 0..3)
#pragma unroll
        for (int j = 0; j < 4; j++) bfr[j] = DSRB(j, 0, bi);
#pragma unroll
        for (int i = 0; i < 4; i++) af[i] = DSRA(i, 0, bi);
        STG(0, 0, kn, si);
        __builtin_amdgcn_s_barrier();
        asm volatile("s_waitcnt lgkmcnt(0)" ::: "memory");
        __builtin_amdgcn_s_setprio(1);
#pragma unroll
        for (int i = 0; i < 4; i++)
#pragma unroll
            for (int j = 0; j < 4; j++)
                acc[i][j] = __builtin_amdgcn_mfma_f32_16x16x32_bf16(af[i], bfr[j], acc[i][j], 0, 0, 0);
        __builtin_amdgcn_s_setprio(0);
        __builtin_amdgcn_s_barrier();

        // ---- ph1 (ks=0, frags 4..7)
#pragma unroll
        for (int i = 0; i < 4; i++) af[i] = DSRA(i + 4, 0, bi);
        STG(1, 0, kn, si);
        __builtin_amdgcn_s_barrier();
        asm volatile("s_waitcnt lgkmcnt(0)" ::: "memory");
        __builtin_amdgcn_s_setprio(1);
#pragma unroll
        for (int i = 0; i < 4; i++)
#pragma unroll
            for (int j = 0; j < 4; j++)
                acc[i + 4][j] = __builtin_amdgcn_mfma_f32_16x16x32_bf16(af[i], bfr[j], acc[i + 4][j], 0, 0, 0);
        __builtin_amdgcn_s_setprio(0);
        asm volatile("s_waitcnt vmcnt(4)" ::: "memory");   // A1/B1 of current tile landed
        __builtin_amdgcn_s_barrier();

        // ---- ph2 (ks=1, frags 0..3)
#pragma unroll
        for (int j = 0; j < 4; j++) bfr[j] = DSRB(j, 1, bi);
#pragma unroll
        for (int i = 0; i < 4; i++) af[i] = DSRA(i, 1, bi);
        STG(0, 1, kn, si);
        __builtin_amdgcn_s_barrier();
        asm volatile("s_waitcnt lgkmcnt(0)" ::: "memory");
        __builtin_amdgcn_s_setprio(1);
#pragma unroll
        for (int i = 0; i < 4; i++)
#pragma unroll
            for (int j = 0; j < 4; j++)
                acc[i][j] = __builtin_amdgcn_mfma_f32_16x16x32_bf16(af[i], bfr[j], acc[i][j], 0, 0, 0);
        __builtin_amdgcn_s_setprio(0);
        __builtin_amdgcn_s_barrier();

        // ---- ph3 (ks=1, frags 4..7)
#pragma unroll
        for (int i = 0; i < 4; i++) af[i] = DSRA(i + 4, 1, bi);
        STG(1, 1, kn, si);
        __builtin_amdgcn_s_barrier();
        asm volatile("s_waitcnt lgkmcnt(0)" ::: "memory");
        __builtin_amdgcn_s_setprio(1);
#pragma unroll
        for (int i = 0; i < 4; i++)
#pragma unroll
            for (int j = 0; j < 4; j++)
                acc[i + 4][j] = __builtin_amdgcn_mfma_f32_16x16x32_bf16(af[i], bfr[j], acc[i + 4][j], 0, 0, 0);
        __builtin_amdgcn_s_setprio(0);
        asm volatile("s_waitcnt vmcnt(4)" ::: "memory");   // A0/B0 of next tile landed
        __builtin_amdgcn_s_barrier();
    }

    // ---- peeled last tile (kt=15, bi=1): no staging; drain once before ks=1
    {
        const int bi = 1;
        bf16x8 af[4], bfr[4];
#pragma unroll
        for (int j = 0; j < 4; j++) bfr[j] = DSRB(j, 0, bi);
#pragma unroll
        for (int i = 0; i < 4; i++) af[i] = DSRA(i, 0, bi);
        __builtin_amdgcn_s_setprio(1);
#pragma unroll
        for (int i = 0; i < 4; i++)
#pragma unroll
            for (int j = 0; j < 4; j++)
                acc[i][j] = __builtin_amdgcn_mfma_f32_16x16x32_bf16(af[i], bfr[j], acc[i][j], 0, 0, 0);
        __builtin_amdgcn_s_setprio(0);
#pragma unroll
        for (int i = 0; i < 4; i++) af[i] = DSRA(i + 4, 0, bi);
        __builtin_amdgcn_s_setprio(1);
#pragma unroll
        for (int i = 0; i < 4; i++)
#pragma unroll
            for (int j = 0; j < 4; j++)
                acc[i + 4][j] = __builtin_amdgcn_mfma_f32_16x16x32_bf16(af[i], bfr[j], acc[i + 4][j], 0, 0, 0);
        __builtin_amdgcn_s_setprio(0);
        asm volatile("s_waitcnt vmcnt(0)" ::: "memory");   // last tile's A1/B1 landed
        __builtin_amdgcn_s_barrier();
#pragma unroll
        for (int j = 0; j < 4; j++) bfr[j] = DSRB(j, 1, bi);
#pragma unroll
        for (int i = 0; i < 4; i++) af[i] = DSRA(i, 1, bi);
        __builtin_amdgcn_s_setprio(1);
#pragma unroll
        for (int i = 0; i < 4; i++)
#pragma unroll
            for (int j = 0; j < 4; j++)
                acc[i][j] = __builtin_amdgcn_mfma_f32_16x16x32_bf16(af[i], bfr[j], acc[i][j], 0, 0, 0);
        __builtin_amdgcn_s_setprio(0);
#pragma unroll
        for (int i = 0; i < 4; i++) af[i] = DSRA(i + 4, 1, bi);
        __builtin_amdgcn_s_setprio(1);
#pragma unroll
        for (int i = 0; i < 4; i++)
#pragma unroll
            for (int j = 0; j < 4; j++)
                acc[i + 4][j] = __builtin_amdgcn_mfma_f32_16x16x32_bf16(af[i], bfr[j], acc[i + 4][j], 0, 0, 0);
        __builtin_amdgcn_s_setprio(0);
    }
#undef STG
#undef DSRA
#undef DSRB

    // ---- epilogue
    float bb[4];
#pragma unroll
    for (int j = 0; j < 4; j++) bb[j] = bias[n0 + wn * 64 + j * 16 + lr];
    float sc;
    if (emode == 0) sc = 0.18033688011112042f;             // log2(e)/8 for exp2-domain scores
    else            sc = fminf(fmaxf(rsp[0], 0.f), 0.3f);  // residual scale clamp
#pragma unroll
    for (int i = 0; i < 8; i++) {
        int row = m0 + wm * 128 + i * 16 + kq * 4;
#pragma unroll
        for (int j = 0; j < 4; j++) {
            int col = n0 + wn * 64 + j * 16 + lr;
#pragma unroll
            for (int r = 0; r < 4; r++)
                C[(size_t)(row + r) * 1024 + col] = (bf16)((acc[i][j][r] + bb[j]) * sc);
        }
    }
}

// ---------------------------------------------------------------- K/V GEMM (proven 128^2 structure, 256 blocks)
// id<128: K = atb@wk^T (+bk) -> Kb ; else V = atb@wv^T (+bv) -> Vtb transposed.
__global__ __launch_bounds__(256) void kv_gemm(const bf16* __restrict__ atb,
                                               const bf16* __restrict__ wkb,
                                               const bf16* __restrict__ wvb,
                                               const float* __restrict__ bk,
                                               const float* __restrict__ bv,
                                               bf16* __restrict__ Kb,
                                               bf16* __restrict__ Vtb) {
    __shared__ __align__(16) bf16 As[128 * 32];
    __shared__ __align__(16) bf16 Bs[128 * 32];

    const int id = blockIdx.x;
    int mode, m0, n0;
    const bf16 *Bt; const float* bias;
    if (id < 128) { mode = 1; m0 = (id & 15) * 128; n0 = (id >> 4) * 128; Bt = wkb; bias = bk; }
    else          { int t = id - 128; mode = 2; m0 = (t & 15) * 128; n0 = (t >> 4) * 128; Bt = wvb; bias = bv; }

    const int tid  = threadIdx.x;
    const int lane = tid & 63;
    const int wv   = tid >> 6;
    const int wr   = wv >> 1, wc = wv & 1;
    const int lr   = lane & 15, kq = lane >> 4;

    fx4 acc[4][4] = {};

    const bf16* Ag = atb + (size_t)m0 * 1024;
    const bf16* Bg = Bt  + (size_t)n0 * 1024;
    const int c0 = tid, c1 = tid + 256;
    const int row0 = c0 >> 2, kc0 = c0 & 3;
    const int row1 = c1 >> 2, kc1 = c1 & 3;

    for (int k0 = 0; k0 < 1024; k0 += 32) {
        gl_lds16(Ag + (size_t)row0 * 1024 + k0 + kc0 * 8, &As[c0 * 8]);
        gl_lds16(Ag + (size_t)row1 * 1024 + k0 + kc1 * 8, &As[c1 * 8]);
        gl_lds16(Bg + (size_t)row0 * 1024 + k0 + kc0 * 8, &Bs[c0 * 8]);
        gl_lds16(Bg + (size_t)row1 * 1024 + k0 + kc1 * 8, &Bs[c1 * 8]);
        __syncthreads();
        bf16x8 af[4], bfr[4];
#pragma unroll
        for (int i = 0; i < 4; i++) af[i]  = *(const bf16x8*)&As[(wr * 64 + i * 16 + lr) * 32 + kq * 8];
#pragma unroll
        for (int j = 0; j < 4; j++) bfr[j] = *(const bf16x8*)&Bs[(wc * 64 + j * 16 + lr) * 32 + kq * 8];
#pragma unroll
        for (int i = 0; i < 4; i++)
#pragma unroll
            for (int j = 0; j < 4; j++)
                acc[i][j] = __builtin_amdgcn_mfma_f32_16x16x32_bf16(af[i], bfr[j], acc[i][j], 0, 0, 0);
        __syncthreads();
    }

    float bb[4];
#pragma unroll
    for (int j = 0; j < 4; j++) bb[j] = bias[n0 + wc * 64 + j * 16 + lr];

    if (mode == 1) {
#pragma unroll
        for (int i = 0; i < 4; i++) {
            int row = m0 + wr * 64 + i * 16 + kq * 4;
#pragma unroll
            for (int j = 0; j < 4; j++) {
                int col = n0 + wc * 64 + j * 16 + lr;
#pragma unroll
                for (int r = 0; r < 4; r++)
                    Kb[(size_t)(row + r) * 1024 + col] = (bf16)(acc[i][j][r] + bb[j]);
            }
        }
    } else {
        // V: transposed output, r-contiguous -> packed bf16x4 stores
#pragma unroll
        for (int i = 0; i < 4; i++) {
            int m = m0 + wr * 64 + i * 16 + kq * 4;  // m = b*512 + a
            int bidx = m >> 9, a = m & 511;
#pragma unroll
            for (int j = 0; j < 4; j++) {
                int col = n0 + wc * 64 + j * 16 + lr;
                bf16x4 o;
#pragma unroll
                for (int r = 0; r < 4; r++) o[r] = (bf16)(acc[i][j][r] + bb[j]);
                *(bf16x4*)&Vtb[((size_t)bidx * H_ + col) * A_ + a] = o;
            }
        }
    }
}

// ---------------------------------------------------------------- attention
// S^T = K·Q^T keeps P in registers (A-operand layout via free k-permutation);
// permuted V^T LDS layout makes every PV B-fragment one conflict-free b128.
// R5: exp2 written straight into PV A-fragments; denominator via ones-B MFMA
// (row layout kq*4+r, broadcast across lr) — no cross-lane reduce, no dnm LDS.
__global__ __launch_bounds__(256, 4) void attn_kernel(const bf16* __restrict__ Q,
                                                      const bf16* __restrict__ Kb,
                                                      const bf16* __restrict__ Vt,
                                                      const int* __restrict__ mask,
                                                      bf16* __restrict__ ctx) {
    __shared__ __align__(16) bf16 Qs[128 * 72];   // padded; reused for ctx staging
    __shared__ __align__(16) bf16 Ks[64 * 72];    // K [a][d], padded
    __shared__ __align__(16) bf16 Vts[64 * 72];   // V^T [d][a-permuted], padded
    __shared__ float smask[512];                  // caps: +/- 50*log2e

    const int tid  = threadIdx.x;
    const int lane = tid & 63;
    const int wv   = tid >> 6;
    const int lr   = lane & 15, kq = lane >> 4;
    const int st = blockIdx.x, h = blockIdx.y, b = blockIdx.z;
    const int m0 = b * S_ + st * 128;
    const float LO = -72.134752f;                 // -50*log2e

    // --- stage Q (padded, via VGPRs) + mask caps
    bf16x8 qtmp[4];
#pragma unroll
    for (int i = 0; i < 4; i++) {
        int c = tid + i * 256, row = c >> 3, ch = c & 7;
        qtmp[i] = *(const bf16x8*)(Q + (size_t)(m0 + row) * H_ + h * 64 + ch * 8);
    }
    smask[tid]       = (mask[b * A_ + tid] > 0)       ? -LO : LO;
    smask[tid + 256] = (mask[b * A_ + tid + 256] > 0) ? -LO : LO;
#pragma unroll
    for (int i = 0; i < 4; i++) {
        int c = tid + i * 256, row = c >> 3, ch = c & 7;
        *(bf16x8*)&Qs[row * 72 + ch * 8] = qtmp[i];
    }

    // staging coords
    const int srow = tid >> 2, sseg = tid & 3;
    const size_t kg = (size_t)(b * A_ + srow) * H_ + h * 64 + sseg * 16;
    const bf16* vrow = Vt + (size_t)(b * H_ + h * 64 + srow) * A_;
    const int va0 = 32 * (sseg >> 1) + 4 * ((2 * sseg) & 3);      // u=0 source base
    const int va1 = 32 * (sseg >> 1) + 4 * ((2 * sseg + 1) & 3);  // u=1 source base

    // prefetch tile 0
    bf16x8 kr0 = *(const bf16x8*)(Kb + kg);
    bf16x8 kr1 = *(const bf16x8*)(Kb + kg + 8);
    bf16x4 v00 = *(const bf16x4*)(vrow + va0);
    bf16x4 v01 = *(const bf16x4*)(vrow + va0 + 16);
    bf16x4 v10 = *(const bf16x4*)(vrow + va1);
    bf16x4 v11 = *(const bf16x4*)(vrow + va1 + 16);

    fx4 acco[2][4] = {};          // [st][dt] : ctx[s=wv*32+st*16+kq*4+r][d=dt*16+lr]
    fx4 accd[2] = {};             // denom:    D[s=...+kq*4+r] (all lr identical)

    bf16x8 vone;
#pragma unroll
    for (int e = 0; e < 8; e++) vone[e] = (bf16)1.0f;

    for (int it = 0; it < 8; it++) {
        const int a0 = it * 64;
        __syncthreads();  // prev compute done reading Ks/Vts (it=0: Q/mask writes ordered)
        *(bf16x8*)&Ks[srow * 72 + sseg * 16]      = kr0;
        *(bf16x8*)&Ks[srow * 72 + sseg * 16 + 8]  = kr1;
        *(bf16x8*)&Vts[srow * 72 + sseg * 16] =
            __builtin_shufflevector(v00, v01, 0, 1, 2, 3, 4, 5, 6, 7);
        *(bf16x8*)&Vts[srow * 72 + sseg * 16 + 8] =
            __builtin_shufflevector(v10, v11, 0, 1, 2, 3, 4, 5, 6, 7);
        __syncthreads();  // staging visible (lgkm only — no LDS-writing vmem in flight)

        if (it < 7) {     // register prefetch for it+1 (uniform branch)
            const size_t ko = kg + (size_t)(a0 + 64) * H_;
            kr0 = *(const bf16x8*)(Kb + ko);
            kr1 = *(const bf16x8*)(Kb + ko + 8);
            v00 = *(const bf16x4*)(vrow + a0 + 64 + va0);
            v01 = *(const bf16x4*)(vrow + a0 + 64 + va0 + 16);
            v10 = *(const bf16x4*)(vrow + a0 + 64 + va1);
            v11 = *(const bf16x4*)(vrow + a0 + 64 + va1 + 16);
        }

        // ---- S^T = K·Q^T  (M=a 64, N=s; wave owns s in [wv*32, wv*32+32))
        fx4 accs[4][2] = {};   // [mt][nt] : S^T[a=mt*16+kq*4+r][s=wv*32+nt*16+lr]
#pragma unroll
        for (int kk = 0; kk < 64; kk += 32) {
            bf16x8 kf[4], qf[2];
#pragma unroll
            for (int mt = 0; mt < 4; mt++)
                kf[mt] = *(const bf16x8*)&Ks[(mt * 16 + lr) * 72 + kk + kq * 8];
#pragma unroll
            for (int nt = 0; nt < 2; nt++)
                qf[nt] = *(const bf16x8*)&Qs[(wv * 32 + nt * 16 + lr) * 72 + kk + kq * 8];
#pragma unroll
            for (int mt = 0; mt < 4; mt++)
#pragma unroll
                for (int nt = 0; nt < 2; nt++)
                    accs[mt][nt] = __builtin_amdgcn_mfma_f32_16x16x32_bf16(kf[mt], qf[nt], accs[mt][nt], 0, 0, 0);
        }

        // ---- softmax numerator in-register, written directly into PV A-fragments
        bf16x8 pa[2][2];   // [ks][stl] : element (mt&1)*4+r <- P[a=a0+mt*16+kq*4+r][s-blk stl]
#pragma unroll
        for (int mt = 0; mt < 4; mt++) {
            fx4 cap = *(const fx4*)&smask[a0 + mt * 16 + kq * 4];
#pragma unroll
            for (int nt = 0; nt < 2; nt++) {
#pragma unroll
                for (int r = 0; r < 4; r++) {
                    float p = __builtin_amdgcn_exp2f(fminf(accs[mt][nt][r], cap[r]));
                    pa[mt >> 1][nt][(mt & 1) * 4 + r] = (bf16)p;
                }
            }
        }

        // ---- PV: ctx += P·V (B = V^T LDS, b128) ; denom += P·1 on the MFMA pipe
#pragma unroll
        for (int ks = 0; ks < 2; ks++) {
#pragma unroll
            for (int stl = 0; stl < 2; stl++)
                accd[stl] = __builtin_amdgcn_mfma_f32_16x16x32_bf16(pa[ks][stl], vone, accd[stl], 0, 0, 0);
#pragma unroll
            for (int dt = 0; dt < 4; dt++) {
                bf16x8 vf = *(const bf16x8*)&Vts[(dt * 16 + lr) * 72 + ks * 32 + kq * 8];
#pragma unroll
                for (int stl = 0; stl < 2; stl++)
                    acco[stl][dt] = __builtin_amdgcn_mfma_f32_16x16x32_bf16(pa[ks][stl], vf, acco[stl][dt], 0, 0, 0);
            }
        }
    }

    // ---- normalize from accd + stage ctx tile into Qs, then vectorized store
#pragma unroll
    for (int stl = 0; stl < 2; stl++) {
        float ri[4];
#pragma unroll
        for (int r = 0; r < 4; r++) ri[r] = __builtin_amdgcn_rcpf(accd[stl][r]);
#pragma unroll
        for (int dt = 0; dt < 4; dt++)
#pragma unroll
            for (int r = 0; r < 4; r++)
                Qs[(wv * 32 + stl * 16 + kq * 4 + r) * 72 + dt * 16 + lr] =
                    (bf16)(acco[stl][dt][r] * ri[r]);
    }
    __syncthreads();
#pragma unroll
    for (int i = 0; i < 4; i++) {
        int c = tid + i * 256, row = c >> 3, ch = c & 7;
        *(bf16x8*)&ctx[(size_t)(m0 + row) * H_ + h * 64 + ch * 8] = *(const bf16x8*)&Qs[row * 72 + ch * 8];
    }
}

// ---------------------------------------------------------------- LayerNorm: bf16 delta -> fp32 out
__global__ __launch_bounds__(256) void ln_kernel(const bf16* __restrict__ in,
                                                 float* __restrict__ out,
                                                 const float* __restrict__ gamma,
                                                 const float* __restrict__ beta) {
    __shared__ float red[8];
    const int tid = threadIdx.x;
    bf16x4 xb = *(const bf16x4*)&in[(size_t)blockIdx.x * 1024 + tid * 4];
    float x0 = (float)xb[0], x1 = (float)xb[1], x2 = (float)xb[2], x3 = (float)xb[3];
    float s = x0 + x1 + x2 + x3;
    float q = x0 * x0 + x1 * x1 + x2 * x2 + x3 * x3;
#pragma unroll
    for (int off = 32; off > 0; off >>= 1) {
        s += __shfl_down(s, off);
        q += __shfl_down(q, off);
    }
    if ((tid & 63) == 0) { red[(tid >> 6) * 2] = s; red[(tid >> 6) * 2 + 1] = q; }
    __syncthreads();
    s = red[0] + red[2] + red[4] + red[6];
    q = red[1] + red[3] + red[5] + red[7];
    float mean = s * (1.f / 1024.f);
    float var  = q * (1.f / 1024.f) - mean * mean;
    float inv  = rsqrtf(var + 1e-5f);
    float4 g  = ((const float4*)gamma)[tid];
    float4 bb = ((const float4*)beta)[tid];
    float4 y;
    y.x = (x0 - mean) * inv * g.x + bb.x;
    y.y = (x1 - mean) * inv * g.y + bb.y;
    y.z = (x2 - mean) * inv * g.z + bb.z;
    y.w = (x3 - mean) * inv * g.w + bb.w;
    ((float4*)(out + (size_t)blockIdx.x * 1024))[tid] = y;
}

// ---------------------------------------------------------------- launch
extern "C" void kernel_launch(void* const* d_in, const int* in_sizes, int n_in,
                              void* d_out, int out_size, void* d_ws, size_t ws_size,
                              hipStream_t stream) {
    const float* hs    = (const float*)d_in[0];
    const float* at    = (const float*)d_in[1];
    const int*   maskp = (const int*)d_in[2];
    const float* Wq    = (const float*)d_in[3];
    const float* bq    = (const float*)d_in[4];
    const float* Wk    = (const float*)d_in[5];
    const float* bk    = (const float*)d_in[6];
    const float* Wv    = (const float*)d_in[7];
    const float* bv    = (const float*)d_in[8];
    const float* Wo    = (const float*)d_in[9];
    const float* bo    = (const float*)d_in[10];
    const float* gamma = (const float*)d_in[11];
    const float* beta  = (const float*)d_in[12];
    const float* rsp   = (const float*)d_in[13];

    char* ws = (char*)d_ws;
    bf16* hsb = (bf16*)(ws + 0);          // 32 MB  [16384,1024]
    bf16* ctx = (bf16*)(ws + 0);          // alias (hs dead after Q gemm)
    bf16* atb = (bf16*)(ws + 33554432);   //  4 MB  [2048,1024]
    bf16* wqb = (bf16*)(ws + 37748736);   //  2 MB
    bf16* wkb = (bf16*)(ws + 39845888);   //  2 MB
    bf16* wvb = (bf16*)(ws + 41943040);   //  2 MB
    bf16* wob = (bf16*)(ws + 44040192);   //  2 MB
    bf16* Qb  = (bf16*)(ws + 46137344);   // 32 MB  [16384,1024] (prescaled)
    bf16* Ob  = Qb;                       // alias (Qb dead after attn) — bf16 delta
    bf16* Kb  = (bf16*)(ws + 79691776);   //  4 MB  [2048,1024]
    bf16* Vtb = (bf16*)(ws + 83886080);   //  4 MB  [B*H, 512] transposed

    cast_all<<<22528, 256, 0, stream>>>(hs, at, Wq, Wk, Wv, Wo,
                                        hsb, atb, wqb, wkb, wvb, wob);

    kv_gemm<<<256, 256, 0, stream>>>(atb, wkb, wvb, bk, bv, Kb, Vtb);

    gemm256<<<256, 512, 0, stream>>>(hsb, wqb, bq, Qb, 0, rsp);

    attn_kernel<<<dim3(32, 16, 4), 256, 0, stream>>>(Qb, Kb, Vtb, maskp, ctx);

    gemm256<<<256, 512, 0, stream>>>(ctx, wob, bo, Ob, 1, rsp);
    ln_kernel<<<16384, 256, 0, stream>>>(Ob, (float*)d_out, gamma, beta);
}

// Round 4
// 308.143 us; speedup vs baseline: 1.0640x; 1.0365x over previous
//
#include <hip/hip_runtime.h>
#include <hip/hip_bf16.h>
#include <cstdint>
#include <cstddef>

// Problem constants
#define B_  4
#define S_  4096
#define A_  512
#define H_  1024
#define NH_ 16
#define HD_ 64

typedef __bf16 bf16;
typedef __bf16 bf16x8 __attribute__((ext_vector_type(8)));
typedef __bf16 bf16x4 __attribute__((ext_vector_type(4)));
typedef float  fx4    __attribute__((ext_vector_type(4)));

typedef __attribute__((address_space(3))) void LDS_v;
typedef const __attribute__((address_space(1))) void GLB_v;

__device__ __forceinline__ void gl_lds16(const void* g, void* l) {
    __builtin_amdgcn_global_load_lds((GLB_v*)g, (LDS_v*)l, 16, 0, 0);
}

__device__ __forceinline__ float sanf(float x) {
    if (x != x) return 0.f;                       // NaN -> 0
    if (fabsf(x) == __builtin_inff()) return x > 0.f ? 10000.f : -10000.f;
    return x;
}

// ---------------------------------------------------------------- fused cast (all 6 inputs, one dispatch)
__global__ __launch_bounds__(256) void cast_all(const float* __restrict__ hs,
                                                const float* __restrict__ at,
                                                const float* __restrict__ wq,
                                                const float* __restrict__ wk,
                                                const float* __restrict__ wv,
                                                const float* __restrict__ wo,
                                                bf16* __restrict__ dhs, bf16* __restrict__ dat,
                                                bf16* __restrict__ dwq, bf16* __restrict__ dwk,
                                                bf16* __restrict__ dwv, bf16* __restrict__ dwo) {
    int i = blockIdx.x * 256 + threadIdx.x;
    const float* s; bf16* d; int off;
    if (i < 4194304)      { s = hs; d = dhs; off = i; }
    else if (i < 4718592) { s = at; d = dat; off = i - 4194304; }
    else if (i < 4980736) { s = wq; d = dwq; off = i - 4718592; }
    else if (i < 5242880) { s = wk; d = dwk; off = i - 4980736; }
    else if (i < 5505024) { s = wv; d = dwv; off = i - 5242880; }
    else                  { s = wo; d = dwo; off = i - 5505024; }
    float4 v = ((const float4*)s)[off];
    bf16x4 o;
    o[0] = (bf16)sanf(v.x); o[1] = (bf16)sanf(v.y);
    o[2] = (bf16)sanf(v.z); o[3] = (bf16)sanf(v.w);
    *(bf16x4*)&d[(size_t)off * 4] = o;
}

// ---------------------------------------------------------------- 256x256 4-phase counted-vmcnt GEMM (R8)
// Same schedule as R7 (m201 template). R8 change: XCD/L2-aware tile mapping —
// XCD k owns m-tiles [8k,8k+8), with the 4 n-tiles of each m-panel ADJACENT
// (concurrent CUs on one XCD share the 0.5MB A-panel via that XCD's L2).
// Previous mapping spread an A-panel's n-tiles across 4 XCDs -> 4x A fetch;
// at K=1024 the block arithmetic intensity (238 FLOP/B) is below the chip
// ratio (396), so that over-fetch costs wall time.
__global__ __launch_bounds__(512, 2) void gemm256(const bf16* __restrict__ A,
                                                  const bf16* __restrict__ Bt,
                                                  const float* __restrict__ bias,
                                                  bf16* __restrict__ C,
                                                  const int emode,
                                                  const float* __restrict__ rsp) {
    __shared__ __align__(16) bf16 lds[2][2][2][256][32];   // [buf][A/B][khalf][row][k] = 128 KiB

    const int tid  = threadIdx.x;
    const int lane = tid & 63;
    const int w8   = tid >> 6;               // wave 0..7
    const int wm   = w8 >> 2, wn = w8 & 3;   // wave grid 2(M) x 4(N)
    const int lr   = lane & 15, kq = lane >> 4;
    const int swz  = ((lr >> 3) & 1) << 4;   // read-side st_16x32 swizzle (elems)

    // XCD/L2-aware mapping: xcd = bid%8 (HW round-robin); within an XCD,
    // 8 m-panels x 4 n-tiles, n-tiles adjacent (A-panel reuse in that L2).
    const int xcd = blockIdx.x & 7;
    const int j   = blockIdx.x >> 3;         // 0..31
    const int m0  = (xcd * 8 + (j >> 2)) << 8;
    const int n0  = (j & 3) << 8;

    // staging source: lane l covers granule g (16B) of its wave's 16-row block;
    // g = l ^ ((l>>5&1)<<1) pre-applies the inverse LDS swizzle.
    const int g = lane ^ (((lane >> 5) & 1) << 1);
    const bf16* Asrc = A  + (size_t)(m0 + w8 * 32 + (g >> 2)) * 1024 + (g & 3) * 8;
    const bf16* Bsrc = Bt + (size_t)(n0 + w8 * 32 + (g >> 2)) * 1024 + (g & 3) * 8;

#define STG(MS_, kh_, kt_, si_) do {                                                   \
        const bf16* s_ = (MS_ ? Bsrc : Asrc) + (kt_) * 64 + (kh_) * 32;                \
        gl_lds16(s_,                 &lds[si_][MS_][kh_][w8 * 32][0]      + lane * 8); \
        gl_lds16(s_ + (size_t)16384, &lds[si_][MS_][kh_][w8 * 32 + 16][0] + lane * 8); \
    } while (0)

#define DSRA(i_, ks_, bi_) (*(const bf16x8*)(&lds[bi_][0][ks_][0][0] + \
        ((((wm * 128 + (i_) * 16 + lr) * 32 + kq * 8)) ^ swz)))
#define DSRB(j_, ks_, bi_) (*(const bf16x8*)(&lds[bi_][1][ks_][0][0] + \
        ((((wn * 64 + (j_) * 16 + lr) * 32 + kq * 8)) ^ swz)))

    fx4 acc[8][4] = {};

    // prologue: stage all 4 halves of tile 0 (order A0,B0,A1,B1), wait first 2
    STG(0, 0, 0, 0); STG(1, 0, 0, 0); STG(0, 1, 0, 0); STG(1, 1, 0, 0);
    asm volatile("s_waitcnt vmcnt(4)" ::: "memory");
    __builtin_amdgcn_s_barrier();

    for (int kt = 0; kt < 15; ++kt) {
        const int bi = kt & 1, si = bi ^ 1, kn = kt + 1;
        bf16x8 af[4], bfr[4];

        // ---- ph0 (ks=0, frags 0..3)
#pragma unroll
        for (int j2 = 0; j2 < 4; j2++) bfr[j2] = DSRB(j2, 0, bi);
#pragma unroll
        for (int i = 0; i < 4; i++) af[i] = DSRA(i, 0, bi);
        STG(0, 0, kn, si);
        __builtin_amdgcn_s_barrier();
        asm volatile("s_waitcnt lgkmcnt(0)" ::: "memory");
        __builtin_amdgcn_s_setprio(1);
#pragma unroll
        for (int i = 0; i < 4; i++)
#pragma unroll
            for (int j2 = 0; j2 < 4; j2++)
                acc[i][j2] = __builtin_amdgcn_mfma_f32_16x16x32_bf16(af[i], bfr[j2], acc[i][j2], 0, 0, 0);
        __builtin_amdgcn_s_setprio(0);
        __builtin_amdgcn_s_barrier();

        // ---- ph1 (ks=0, frags 4..7)
#pragma unroll
        for (int i = 0; i < 4; i++) af[i] = DSRA(i + 4, 0, bi);
        STG(1, 0, kn, si);
        __builtin_amdgcn_s_barrier();
        asm volatile("s_waitcnt lgkmcnt(0)" ::: "memory");
        __builtin_amdgcn_s_setprio(1);
#pragma unroll
        for (int i = 0; i < 4; i++)
#pragma unroll
            for (int j2 = 0; j2 < 4; j2++)
                acc[i + 4][j2] = __builtin_amdgcn_mfma_f32_16x16x32_bf16(af[i], bfr[j2], acc[i + 4][j2], 0, 0, 0);
        __builtin_amdgcn_s_setprio(0);
        asm volatile("s_waitcnt vmcnt(4)" ::: "memory");   // A1/B1 of current tile landed
        __builtin_amdgcn_s_barrier();

        // ---- ph2 (ks=1, frags 0..3)
#pragma unroll
        for (int j2 = 0; j2 < 4; j2++) bfr[j2] = DSRB(j2, 1, bi);
#pragma unroll
        for (int i = 0; i < 4; i++) af[i] = DSRA(i, 1, bi);
        STG(0, 1, kn, si);
        __builtin_amdgcn_s_barrier();
        asm volatile("s_waitcnt lgkmcnt(0)" ::: "memory");
        __builtin_amdgcn_s_setprio(1);
#pragma unroll
        for (int i = 0; i < 4; i++)
#pragma unroll
            for (int j2 = 0; j2 < 4; j2++)
                acc[i][j2] = __builtin_amdgcn_mfma_f32_16x16x32_bf16(af[i], bfr[j2], acc[i][j2], 0, 0, 0);
        __builtin_amdgcn_s_setprio(0);
        __builtin_amdgcn_s_barrier();

        // ---- ph3 (ks=1, frags 4..7)
#pragma unroll
        for (int i = 0; i < 4; i++) af[i] = DSRA(i + 4, 1, bi);
        STG(1, 1, kn, si);
        __builtin_amdgcn_s_barrier();
        asm volatile("s_waitcnt lgkmcnt(0)" ::: "memory");
        __builtin_amdgcn_s_setprio(1);
#pragma unroll
        for (int i = 0; i < 4; i++)
#pragma unroll
            for (int j2 = 0; j2 < 4; j2++)
                acc[i + 4][j2] = __builtin_amdgcn_mfma_f32_16x16x32_bf16(af[i], bfr[j2], acc[i + 4][j2], 0, 0, 0);
        __builtin_amdgcn_s_setprio(0);
        asm volatile("s_waitcnt vmcnt(4)" ::: "memory");   // A0/B0 of next tile landed
        __builtin_amdgcn_s_barrier();
    }

    // ---- peeled last tile (kt=15, bi=1): no staging; drain once before ks=1
    {
        const int bi = 1;
        bf16x8 af[4], bfr[4];
#pragma unroll
        for (int j2 = 0; j2 < 4; j2++) bfr[j2] = DSRB(j2, 0, bi);
#pragma unroll
        for (int i = 0; i < 4; i++) af[i] = DSRA(i, 0, bi);
        __builtin_amdgcn_s_setprio(1);
#pragma unroll
        for (int i = 0; i < 4; i++)
#pragma unroll
            for (int j2 = 0; j2 < 4; j2++)
                acc[i][j2] = __builtin_amdgcn_mfma_f32_16x16x32_bf16(af[i], bfr[j2], acc[i][j2], 0, 0, 0);
        __builtin_amdgcn_s_setprio(0);
#pragma unroll
        for (int i = 0; i < 4; i++) af[i] = DSRA(i + 4, 0, bi);
        __builtin_amdgcn_s_setprio(1);
#pragma unroll
        for (int i = 0; i < 4; i++)
#pragma unroll
            for (int j2 = 0; j2 < 4; j2++)
                acc[i + 4][j2] = __builtin_amdgcn_mfma_f32_16x16x32_bf16(af[i], bfr[j2], acc[i + 4][j2], 0, 0, 0);
        __builtin_amdgcn_s_setprio(0);
        asm volatile("s_waitcnt vmcnt(0)" ::: "memory");   // last tile's A1/B1 landed
        __builtin_amdgcn_s_barrier();
#pragma unroll
        for (int j2 = 0; j2 < 4; j2++) bfr[j2] = DSRB(j2, 1, bi);
#pragma unroll
        for (int i = 0; i < 4; i++) af[i] = DSRA(i, 1, bi);
        __builtin_amdgcn_s_setprio(1);
#pragma unroll
        for (int i = 0; i < 4; i++)
#pragma unroll
            for (int j2 = 0; j2 < 4; j2++)
                acc[i][j2] = __builtin_amdgcn_mfma_f32_16x16x32_bf16(af[i], bfr[j2], acc[i][j2], 0, 0, 0);
        __builtin_amdgcn_s_setprio(0);
#pragma unroll
        for (int i = 0; i < 4; i++) af[i] = DSRA(i + 4, 1, bi);
        __builtin_amdgcn_s_setprio(1);
#pragma unroll
        for (int i = 0; i < 4; i++)
#pragma unroll
            for (int j2 = 0; j2 < 4; j2++)
                acc[i + 4][j2] = __builtin_amdgcn_mfma_f32_16x16x32_bf16(af[i], bfr[j2], acc[i + 4][j2], 0, 0, 0);
        __builtin_amdgcn_s_setprio(0);
    }
#undef STG
#undef DSRA
#undef DSRB

    // ---- epilogue
    float bb[4];
#pragma unroll
    for (int j2 = 0; j2 < 4; j2++) bb[j2] = bias[n0 + wn * 64 + j2 * 16 + lr];
    float sc;
    if (emode == 0) sc = 0.18033688011112042f;             // log2(e)/8 for exp2-domain scores
    else            sc = fminf(fmaxf(rsp[0], 0.f), 0.3f);  // residual scale clamp
#pragma unroll
    for (int i = 0; i < 8; i++) {
        int row = m0 + wm * 128 + i * 16 + kq * 4;
#pragma unroll
        for (int j2 = 0; j2 < 4; j2++) {
            int col = n0 + wn * 64 + j2 * 16 + lr;
#pragma unroll
            for (int r = 0; r < 4; r++)
                C[(size_t)(row + r) * 1024 + col] = (bf16)((acc[i][j2][r] + bb[j2]) * sc);
        }
    }
}

// ---------------------------------------------------------------- K/V GEMM (proven 128^2 structure, 256 blocks)
// id<128: K = atb@wk^T (+bk) -> Kb ; else V = atb@wv^T (+bv) -> Vtb transposed.
__global__ __launch_bounds__(256) void kv_gemm(const bf16* __restrict__ atb,
                                               const bf16* __restrict__ wkb,
                                               const bf16* __restrict__ wvb,
                                               const float* __restrict__ bk,
                                               const float* __restrict__ bv,
                                               bf16* __restrict__ Kb,
                                               bf16* __restrict__ Vtb) {
    __shared__ __align__(16) bf16 As[128 * 32];
    __shared__ __align__(16) bf16 Bs[128 * 32];

    const int id = blockIdx.x;
    int mode, m0, n0;
    const bf16 *Bt; const float* bias;
    if (id < 128) { mode = 1; m0 = (id & 15) * 128; n0 = (id >> 4) * 128; Bt = wkb; bias = bk; }
    else          { int t = id - 128; mode = 2; m0 = (t & 15) * 128; n0 = (t >> 4) * 128; Bt = wvb; bias = bv; }

    const int tid  = threadIdx.x;
    const int lane = tid & 63;
    const int wv   = tid >> 6;
    const int wr   = wv >> 1, wc = wv & 1;
    const int lr   = lane & 15, kq = lane >> 4;

    fx4 acc[4][4] = {};

    const bf16* Ag = atb + (size_t)m0 * 1024;
    const bf16* Bg = Bt  + (size_t)n0 * 1024;
    const int c0 = tid, c1 = tid + 256;
    const int row0 = c0 >> 2, kc0 = c0 & 3;
    const int row1 = c1 >> 2, kc1 = c1 & 3;

    for (int k0 = 0; k0 < 1024; k0 += 32) {
        gl_lds16(Ag + (size_t)row0 * 1024 + k0 + kc0 * 8, &As[c0 * 8]);
        gl_lds16(Ag + (size_t)row1 * 1024 + k0 + kc1 * 8, &As[c1 * 8]);
        gl_lds16(Bg + (size_t)row0 * 1024 + k0 + kc0 * 8, &Bs[c0 * 8]);
        gl_lds16(Bg + (size_t)row1 * 1024 + k0 + kc1 * 8, &Bs[c1 * 8]);
        __syncthreads();
        bf16x8 af[4], bfr[4];
#pragma unroll
        for (int i = 0; i < 4; i++) af[i]  = *(const bf16x8*)&As[(wr * 64 + i * 16 + lr) * 32 + kq * 8];
#pragma unroll
        for (int j = 0; j < 4; j++) bfr[j] = *(const bf16x8*)&Bs[(wc * 64 + j * 16 + lr) * 32 + kq * 8];
#pragma unroll
        for (int i = 0; i < 4; i++)
#pragma unroll
            for (int j = 0; j < 4; j++)
                acc[i][j] = __builtin_amdgcn_mfma_f32_16x16x32_bf16(af[i], bfr[j], acc[i][j], 0, 0, 0);
        __syncthreads();
    }

    float bb[4];
#pragma unroll
    for (int j = 0; j < 4; j++) bb[j] = bias[n0 + wc * 64 + j * 16 + lr];

    if (mode == 1) {
#pragma unroll
        for (int i = 0; i < 4; i++) {
            int row = m0 + wr * 64 + i * 16 + kq * 4;
#pragma unroll
            for (int j = 0; j < 4; j++) {
                int col = n0 + wc * 64 + j * 16 + lr;
#pragma unroll
                for (int r = 0; r < 4; r++)
                    Kb[(size_t)(row + r) * 1024 + col] = (bf16)(acc[i][j][r] + bb[j]);
            }
        }
    } else {
        // V: transposed output, r-contiguous -> packed bf16x4 stores
#pragma unroll
        for (int i = 0; i < 4; i++) {
            int m = m0 + wr * 64 + i * 16 + kq * 4;  // m = b*512 + a
            int bidx = m >> 9, a = m & 511;
#pragma unroll
            for (int j = 0; j < 4; j++) {
                int col = n0 + wc * 64 + j * 16 + lr;
                bf16x4 o;
#pragma unroll
                for (int r = 0; r < 4; r++) o[r] = (bf16)(acc[i][j][r] + bb[j]);
                *(bf16x4*)&Vtb[((size_t)bidx * H_ + col) * A_ + a] = o;
            }
        }
    }
}

// ---------------------------------------------------------------- attention
// S^T = K·Q^T keeps P in registers; permuted V^T LDS layout -> conflict-free
// b128 PV B-fragments. R5: exp2 straight into PV A-fragments; denominator via
// ones-B MFMA. R8: Q-HOIST — each lane's 4 bf16x8 Q fragments loaded from
// global ONCE into registers (no Qs staging pass, no per-tile Qs ds_reads:
// -4 b128/tile and their lgkm stalls). Qs LDS kept only for output staging.
__global__ __launch_bounds__(256, 4) void attn_kernel(const bf16* __restrict__ Q,
                                                      const bf16* __restrict__ Kb,
                                                      const bf16* __restrict__ Vt,
                                                      const int* __restrict__ mask,
                                                      bf16* __restrict__ ctx) {
    __shared__ __align__(16) bf16 Qs[128 * 72];   // output (ctx) staging only
    __shared__ __align__(16) bf16 Ks[64 * 72];    // K [a][d], padded
    __shared__ __align__(16) bf16 Vts[64 * 72];   // V^T [d][a-permuted], padded
    __shared__ float smask[512];                  // caps: +/- 50*log2e

    const int tid  = threadIdx.x;
    const int lane = tid & 63;
    const int wv   = tid >> 6;
    const int lr   = lane & 15, kq = lane >> 4;
    const int st = blockIdx.x, h = blockIdx.y, b = blockIdx.z;
    const int m0 = b * S_ + st * 128;
    const float LO = -72.134752f;                 // -50*log2e

    // --- mask caps to LDS; Q fragments straight to registers (one-time)
    smask[tid]       = (mask[b * A_ + tid] > 0)       ? -LO : LO;
    smask[tid + 256] = (mask[b * A_ + tid + 256] > 0) ? -LO : LO;

    bf16x8 qreg[2][2];   // [kk2][nt] : Q[m0+wv*32+nt*16+lr][h*64+kk2*32+kq*8 ..+8]
#pragma unroll
    for (int kk2 = 0; kk2 < 2; kk2++)
#pragma unroll
        for (int nt = 0; nt < 2; nt++)
            qreg[kk2][nt] = *(const bf16x8*)(Q + (size_t)(m0 + wv * 32 + nt * 16 + lr) * H_
                                              + h * 64 + kk2 * 32 + kq * 8);

    // staging coords
    const int srow = tid >> 2, sseg = tid & 3;
    const size_t kg = (size_t)(b * A_ + srow) * H_ + h * 64 + sseg * 16;
    const bf16* vrow = Vt + (size_t)(b * H_ + h * 64 + srow) * A_;
    const int va0 = 32 * (sseg >> 1) + 4 * ((2 * sseg) & 3);      // u=0 source base
    const int va1 = 32 * (sseg >> 1) + 4 * ((2 * sseg + 1) & 3);  // u=1 source base

    // prefetch tile 0
    bf16x8 kr0 = *(const bf16x8*)(Kb + kg);
    bf16x8 kr1 = *(const bf16x8*)(Kb + kg + 8);
    bf16x4 v00 = *(const bf16x4*)(vrow + va0);
    bf16x4 v01 = *(const bf16x4*)(vrow + va0 + 16);
    bf16x4 v10 = *(const bf16x4*)(vrow + va1);
    bf16x4 v11 = *(const bf16x4*)(vrow + va1 + 16);

    fx4 acco[2][4] = {};          // [st][dt] : ctx[s=wv*32+st*16+kq*4+r][d=dt*16+lr]
    fx4 accd[2] = {};             // denom:    D[s=...+kq*4+r] (all lr identical)

    bf16x8 vone;
#pragma unroll
    for (int e = 0; e < 8; e++) vone[e] = (bf16)1.0f;

    for (int it = 0; it < 8; it++) {
        const int a0 = it * 64;
        __syncthreads();  // prev compute done reading Ks/Vts (it=0: mask writes ordered)
        *(bf16x8*)&Ks[srow * 72 + sseg * 16]      = kr0;
        *(bf16x8*)&Ks[srow * 72 + sseg * 16 + 8]  = kr1;
        *(bf16x8*)&Vts[srow * 72 + sseg * 16] =
            __builtin_shufflevector(v00, v01, 0, 1, 2, 3, 4, 5, 6, 7);
        *(bf16x8*)&Vts[srow * 72 + sseg * 16 + 8] =
            __builtin_shufflevector(v10, v11, 0, 1, 2, 3, 4, 5, 6, 7);
        __syncthreads();  // staging visible (lgkm only — no LDS-writing vmem in flight)

        if (it < 7) {     // register prefetch for it+1 (uniform branch)
            const size_t ko = kg + (size_t)(a0 + 64) * H_;
            kr0 = *(const bf16x8*)(Kb + ko);
            kr1 = *(const bf16x8*)(Kb + ko + 8);
            v00 = *(const bf16x4*)(vrow + a0 + 64 + va0);
            v01 = *(const bf16x4*)(vrow + a0 + 64 + va0 + 16);
            v10 = *(const bf16x4*)(vrow + a0 + 64 + va1);
            v11 = *(const bf16x4*)(vrow + a0 + 64 + va1 + 16);
        }

        // ---- S^T = K·Q^T  (M=a 64, N=s; wave owns s in [wv*32, wv*32+32))
        fx4 accs[4][2] = {};   // [mt][nt] : S^T[a=mt*16+kq*4+r][s=wv*32+nt*16+lr]
#pragma unroll
        for (int kk2 = 0; kk2 < 2; kk2++) {
            bf16x8 kf[4];
#pragma unroll
            for (int mt = 0; mt < 4; mt++)
                kf[mt] = *(const bf16x8*)&Ks[(mt * 16 + lr) * 72 + kk2 * 32 + kq * 8];
#pragma unroll
            for (int mt = 0; mt < 4; mt++)
#pragma unroll
                for (int nt = 0; nt < 2; nt++)
                    accs[mt][nt] = __builtin_amdgcn_mfma_f32_16x16x32_bf16(kf[mt], qreg[kk2][nt], accs[mt][nt], 0, 0, 0);
        }

        // ---- softmax numerator in-register, written directly into PV A-fragments
        bf16x8 pa[2][2];   // [ks][stl] : element (mt&1)*4+r <- P[a=a0+mt*16+kq*4+r][s-blk stl]
#pragma unroll
        for (int mt = 0; mt < 4; mt++) {
            fx4 cap = *(const fx4*)&smask[a0 + mt * 16 + kq * 4];
#pragma unroll
            for (int nt = 0; nt < 2; nt++) {
#pragma unroll
                for (int r = 0; r < 4; r++) {
                    float p = __builtin_amdgcn_exp2f(fminf(accs[mt][nt][r], cap[r]));
                    pa[mt >> 1][nt][(mt & 1) * 4 + r] = (bf16)p;
                }
            }
        }

        // ---- PV: ctx += P·V (B = V^T LDS, b128) ; denom += P·1 on the MFMA pipe
#pragma unroll
        for (int ks = 0; ks < 2; ks++) {
#pragma unroll
            for (int stl = 0; stl < 2; stl++)
                accd[stl] = __builtin_amdgcn_mfma_f32_16x16x32_bf16(pa[ks][stl], vone, accd[stl], 0, 0, 0);
#pragma unroll
            for (int dt = 0; dt < 4; dt++) {
                bf16x8 vf = *(const bf16x8*)&Vts[(dt * 16 + lr) * 72 + ks * 32 + kq * 8];
#pragma unroll
                for (int stl = 0; stl < 2; stl++)
                    acco[stl][dt] = __builtin_amdgcn_mfma_f32_16x16x32_bf16(pa[ks][stl], vf, acco[stl][dt], 0, 0, 0);
            }
        }
    }

    // ---- normalize from accd + stage ctx tile into Qs, then vectorized store
#pragma unroll
    for (int stl = 0; stl < 2; stl++) {
        float ri[4];
#pragma unroll
        for (int r = 0; r < 4; r++) ri[r] = __builtin_amdgcn_rcpf(accd[stl][r]);
#pragma unroll
        for (int dt = 0; dt < 4; dt++)
#pragma unroll
            for (int r = 0; r < 4; r++)
                Qs[(wv * 32 + stl * 16 + kq * 4 + r) * 72 + dt * 16 + lr] =
                    (bf16)(acco[stl][dt][r] * ri[r]);
    }
    __syncthreads();
#pragma unroll
    for (int i = 0; i < 4; i++) {
        int c = tid + i * 256, row = c >> 3, ch = c & 7;
        *(bf16x8*)&ctx[(size_t)(m0 + row) * H_ + h * 64 + ch * 8] = *(const bf16x8*)&Qs[row * 72 + ch * 8];
    }
}

// ---------------------------------------------------------------- LayerNorm: bf16 delta -> fp32 out
__global__ __launch_bounds__(256) void ln_kernel(const bf16* __restrict__ in,
                                                 float* __restrict__ out,
                                                 const float* __restrict__ gamma,
                                                 const float* __restrict__ beta) {
    __shared__ float red[8];
    const int tid = threadIdx.x;
    bf16x4 xb = *(const bf16x4*)&in[(size_t)blockIdx.x * 1024 + tid * 4];
    float x0 = (float)xb[0], x1 = (float)xb[1], x2 = (float)xb[2], x3 = (float)xb[3];
    float s = x0 + x1 + x2 + x3;
    float q = x0 * x0 + x1 * x1 + x2 * x2 + x3 * x3;
#pragma unroll
    for (int off = 32; off > 0; off >>= 1) {
        s += __shfl_down(s, off);
        q += __shfl_down(q, off);
    }
    if ((tid & 63) == 0) { red[(tid >> 6) * 2] = s; red[(tid >> 6) * 2 + 1] = q; }
    __syncthreads();
    s = red[0] + red[2] + red[4] + red[6];
    q = red[1] + red[3] + red[5] + red[7];
    float mean = s * (1.f / 1024.f);
    float var  = q * (1.f / 1024.f) - mean * mean;
    float inv  = rsqrtf(var + 1e-5f);
    float4 g  = ((const float4*)gamma)[tid];
    float4 bb = ((const float4*)beta)[tid];
    float4 y;
    y.x = (x0 - mean) * inv * g.x + bb.x;
    y.y = (x1 - mean) * inv * g.y + bb.y;
    y.z = (x2 - mean) * inv * g.z + bb.z;
    y.w = (x3 - mean) * inv * g.w + bb.w;
    ((float4*)(out + (size_t)blockIdx.x * 1024))[tid] = y;
}

// ---------------------------------------------------------------- launch
extern "C" void kernel_launch(void* const* d_in, const int* in_sizes, int n_in,
                              void* d_out, int out_size, void* d_ws, size_t ws_size,
                              hipStream_t stream) {
    const float* hs    = (const float*)d_in[0];
    const float* at    = (const float*)d_in[1];
    const int*   maskp = (const int*)d_in[2];
    const float* Wq    = (const float*)d_in[3];
    const float* bq    = (const float*)d_in[4];
    const float* Wk    = (const float*)d_in[5];
    const float* bk    = (const float*)d_in[6];
    const float* Wv    = (const float*)d_in[7];
    const float* bv    = (const float*)d_in[8];
    const float* Wo    = (const float*)d_in[9];
    const float* bo    = (const float*)d_in[10];
    const float* gamma = (const float*)d_in[11];
    const float* beta  = (const float*)d_in[12];
    const float* rsp   = (const float*)d_in[13];

    char* ws = (char*)d_ws;
    bf16* hsb = (bf16*)(ws + 0);          // 32 MB  [16384,1024]
    bf16* ctx = (bf16*)(ws + 0);          // alias (hs dead after Q gemm)
    bf16* atb = (bf16*)(ws + 33554432);   //  4 MB  [2048,1024]
    bf16* wqb = (bf16*)(ws + 37748736);   //  2 MB
    bf16* wkb = (bf16*)(ws + 39845888);   //  2 MB
    bf16* wvb = (bf16*)(ws + 41943040);   //  2 MB
    bf16* wob = (bf16*)(ws + 44040192);   //  2 MB
    bf16* Qb  = (bf16*)(ws + 46137344);   // 32 MB  [16384,1024] (prescaled)
    bf16* Ob  = Qb;                       // alias (Qb dead after attn) — bf16 delta
    bf16* Kb  = (bf16*)(ws + 79691776);   //  4 MB  [2048,1024]
    bf16* Vtb = (bf16*)(ws + 83886080);   //  4 MB  [B*H, 512] transposed

    cast_all<<<22528, 256, 0, stream>>>(hs, at, Wq, Wk, Wv, Wo,
                                        hsb, atb, wqb, wkb, wvb, wob);

    kv_gemm<<<256, 256, 0, stream>>>(atb, wkb, wvb, bk, bv, Kb, Vtb);

    gemm256<<<256, 512, 0, stream>>>(hsb, wqb, bq, Qb, 0, rsp);

    attn_kernel<<<dim3(32, 16, 4), 256, 0, stream>>>(Qb, Kb, Vtb, maskp, ctx);

    gemm256<<<256, 512, 0, stream>>>(ctx, wob, bo, Ob, 1, rsp);
    ln_kernel<<<16384, 256, 0, stream>>>(Ob, (float*)d_out, gamma, beta);
}